// Round 1
// baseline (217.407 us; speedup 1.0000x reference)
//
#include <hip/hip_runtime.h>

// Problem constants (RefinementLayer1): B=2, L=192, D=768, NC=4, H=256
#define LSEQ 192
#define DIM  768
#define NCASE 4
#define HID  256
#define BATCH 2

typedef float  floatx4 __attribute__((ext_vector_type(4)));
typedef __bf16 bf16x8  __attribute__((ext_vector_type(8)));

// tanh(x) = 1 - 2/(exp(2x)+1), exp via hw exp2. Saturates correctly at +-inf.
__device__ __forceinline__ float fast_tanh(float x) {
    float e = __builtin_amdgcn_exp2f(x * 2.88539008177793f); // 2*log2(e)
    return 1.0f - 2.0f * __builtin_amdgcn_rcpf(e + 1.0f);
}

// ---------------------------------------------------------------------------
// Kernel 0: pack Wmid[n, k<256, h] (fp32) into bf16 MFMA B-fragment order.
// Fragment layout for mfma_f32_16x16x32_bf16 B-operand:
//   lane holds B[k = (lane>>4)*8 + j][h = lane&15], j = 0..7 contiguous.
// Packed: Bpack[((n*8 + kc)*16 + ct)*512 + lane*8 + j]
//   where k = kc*32 + (lane>>4)*8 + j, h = ct*16 + (lane&15).
// ---------------------------------------------------------------------------
__global__ void pack_wmid(const float* __restrict__ Wmid, __bf16* __restrict__ Bpack) {
    int idx = blockIdx.x * blockDim.x + threadIdx.x;   // 0 .. NCASE*256*256-1
    if (idx >= NCASE * 256 * 256) return;
    int j    = idx & 7;
    int lane = (idx >> 3) & 63;
    int frag = idx >> 9;          // n*128 + kc*16 + ct
    int ct   = frag & 15;
    int kc   = (frag >> 4) & 7;
    int n    = frag >> 7;
    int k = kc * 32 + (lane >> 4) * 8 + j;
    int h = ct * 16 + (lane & 15);
    Bpack[idx] = (__bf16)Wmid[(n * 260 + k) * 256 + h];
}

// ---------------------------------------------------------------------------
// Kernel 1: lin[row, col] = seq[row,:] @ [Wp | Wa][:, col]   (fp32, split-K=4)
// rows = b*L + l (384), cols: [0,256) -> Wp, [256,1280) -> Wa col-256.
// Biases are NOT added here (folded into kernel 2's tanh argument).
// lin must be zeroed before launch (atomicAdd accumulation).
// ---------------------------------------------------------------------------
__global__ __launch_bounds__(256) void lin_gemm(const float* __restrict__ seq,
                                                const float* __restrict__ Wp,
                                                const float* __restrict__ Wa,
                                                float* __restrict__ lin) {
    const int bm = blockIdx.x;   // 6  tiles of 64 rows
    const int bn = blockIdx.y;   // 20 tiles of 64 cols
    const int ks = blockIdx.z;   // 4  K-splits of 192

    __shared__ float As[16][64];   // transposed: As[k][m]
    __shared__ float Bs[16][64];

    const int tid = threadIdx.x;
    const int tx = tid & 15, ty = tid >> 4;
    const int colg0 = bn * 64;

    float acc[4][4] = {};

    for (int k0 = ks * 192; k0 < ks * 192 + 192; k0 += 16) {
        // A loader: m = tid>>2 (64 rows), kq = (tid&3)*4
        const int m = tid >> 2, kq = (tid & 3) * 4;
        floatx4 av = *(const floatx4*)(seq + (size_t)(bm * 64 + m) * DIM + k0 + kq);
        // B loader: kk = tid>>4 (16 k), cq = (tid&15)*4
        const int kk = tid >> 4, cq = (tid & 15) * 4;
        const int colg = colg0 + cq;
        const float* bptr = (colg < 256) ? (Wp + (size_t)(k0 + kk) * HID + colg)
                                         : (Wa + (size_t)(k0 + kk) * (NCASE * HID) + (colg - 256));
        floatx4 bv = *(const floatx4*)bptr;

        __syncthreads();
        for (int i = 0; i < 4; i++) As[kq + i][m] = av[i];
        for (int i = 0; i < 4; i++) Bs[kk][cq + i] = bv[i];
        __syncthreads();

        for (int k = 0; k < 16; k++) {
            float a0 = As[k][ty * 4 + 0];
            float a1 = As[k][ty * 4 + 1];
            float a2 = As[k][ty * 4 + 2];
            float a3 = As[k][ty * 4 + 3];
            floatx4 b = *(const floatx4*)&Bs[k][tx * 4];
            for (int j = 0; j < 4; j++) {
                acc[0][j] += a0 * b[j];
                acc[1][j] += a1 * b[j];
                acc[2][j] += a2 * b[j];
                acc[3][j] += a3 * b[j];
            }
        }
    }
    for (int i = 0; i < 4; i++)
        for (int j = 0; j < 4; j++)
            atomicAdd(&lin[(size_t)(bm * 64 + ty * 4 + i) * 1280 + colg0 + tx * 4 + j],
                      acc[i][j]);
}

// ---------------------------------------------------------------------------
// Kernel 2: fused main. Per block: fixed (b, n), 64-row tile (8 p x 8 a),
// full N=256. A[m,k] = tanh(hp[p,k] + ha[a,n,k] + bp[k] + ba[n*256+k])
// generated into LDS in MFMA A-fragment layout, MFMA over K=256; epilogue
// adds bs.Wmid2 + bmid, tanh, dots with Wout, reduces over h -> out[b,p,n,a].
// MFMA layouts (m89/m91-verified):
//   A: lane holds A[m=lane&15][k=(lane>>4)*8+j]
//   B: lane holds B[k=(lane>>4)*8+j][h=lane&15]
//   C/D: lane reg holds D[row=(lane>>4)*4+reg][col=lane&15]
// ---------------------------------------------------------------------------
__global__ __launch_bounds__(256) void refine_main(
    const float* __restrict__ lin,        // [384][1280]
    const float* __restrict__ base_score, // [B][L][NC][L]
    const float* __restrict__ Wmid,       // [NC][260][256] fp32 (k>=256 rows used)
    const float* __restrict__ bmid,       // [NC][256]
    const float* __restrict__ Wout,       // [NC][256]
    const float* __restrict__ bp,         // [256]
    const float* __restrict__ ba,         // [1024]
    const __bf16* __restrict__ Bpack,     // packed Wmid k<256 bf16
    float* __restrict__ out)              // [B][L][NC][L]
{
    const int bx = blockIdx.x;            // 576 = 24*24
    const int n  = blockIdx.y;
    const int b  = blockIdx.z;
    const int ptile = bx / 24, atile = bx % 24;
    const int p0 = ptile * 8, a0 = atile * 8;

    const int tid   = threadIdx.x;
    const int w     = tid >> 6;           // wave 0..3, owns cols [w*64, w*64+64)
    const int lane  = tid & 63;
    const int quad  = lane >> 4;
    const int col16 = lane & 15;

    __shared__ bf16x8 Alds[256];          // [rt][lane] packed A-frags, 4 KB
    __shared__ float  bs_s[64][4];        // bs[m][k] = base_score[b,p(m),k,a(m)]
    __shared__ float  w2_s[4][256];       // Wmid[n][256+k][h]
    __shared__ float  bwo_s[2][256];      // [0]=bmid[n], [1]=Wout[n]
    __shared__ float  bc_s[256];          // bp[k] + ba[n*256+k]
    __shared__ float  red[4][64];         // cross-wave row partials

    // ---- preload small per-block data (barrier provided by first loop sync)
    for (int i = 0; i < 4; i++)
        w2_s[i][tid] = Wmid[(size_t)(n * 260 + 256 + i) * 256 + tid];
    bwo_s[0][tid] = bmid[n * 256 + tid];
    bwo_s[1][tid] = Wout[n * 256 + tid];
    bc_s[tid]     = bp[tid] + ba[n * 256 + tid];
    {
        int row = tid >> 2, kk = tid & 3;
        int p = p0 + (row >> 3), a = a0 + (row & 7);
        bs_s[row][kk] = base_score[((size_t)(b * LSEQ + p) * NCASE + kk) * LSEQ + a];
    }

    // A-gen assignment: thread generates row m = w*16 + col16, k-slice quad*8..+7
    const int m_gen = w * 16 + col16;
    const int pg = p0 + (m_gen >> 3), ag = a0 + (m_gen & 7);
    const float* hp_ptr = lin + (size_t)(b * LSEQ + pg) * 1280;
    const float* ha_ptr = lin + (size_t)(b * LSEQ + ag) * 1280 + 256 + n * 256;
    const int klo = quad * 8;

    floatx4 acc[4][4] = {};   // [rt][ct]

    for (int kc = 0; kc < 8; kc++) {
        const int k0 = kc * 32;
        // global loads first (no LDS dependence) — L1/L2-hot after first chunk
        floatx4 hp0 = *(const floatx4*)(hp_ptr + k0 + klo);
        floatx4 hp1 = *(const floatx4*)(hp_ptr + k0 + klo + 4);
        floatx4 ha0 = *(const floatx4*)(ha_ptr + k0 + klo);
        floatx4 ha1 = *(const floatx4*)(ha_ptr + k0 + klo + 4);
        bf16x8 bfrag[4];
        for (int ct = 0; ct < 4; ct++)
            bfrag[ct] = *(const bf16x8*)(Bpack +
                ((size_t)((n * 8 + kc) * 16 + (w * 4 + ct)) * 512) + lane * 8);

        __syncthreads();   // protect Alds against previous iteration's reads
        bf16x8 av;
        for (int j = 0; j < 4; j++)
            av[j]     = (__bf16)fast_tanh(hp0[j] + ha0[j] + bc_s[k0 + klo + j]);
        for (int j = 0; j < 4; j++)
            av[4 + j] = (__bf16)fast_tanh(hp1[j] + ha1[j] + bc_s[k0 + klo + 4 + j]);
        Alds[tid] = av;
        __syncthreads();

        bf16x8 af[4];
        for (int rt = 0; rt < 4; rt++) af[rt] = Alds[rt * 64 + lane];
        for (int rt = 0; rt < 4; rt++)
            for (int ct = 0; ct < 4; ct++)
                acc[rt][ct] = __builtin_amdgcn_mfma_f32_16x16x32_bf16(
                    af[rt], bfrag[ct], acc[rt][ct], 0, 0, 0);
    }

    // ---- epilogue: + bs.Wmid2 + bmid, tanh, * Wout, reduce over h
    float wo[4], bm[4], w2r[4][4];
    for (int ct = 0; ct < 4; ct++) {
        int h = w * 64 + ct * 16 + col16;
        wo[ct] = bwo_s[1][h];
        bm[ct] = bwo_s[0][h];
        for (int kk = 0; kk < 4; kk++) w2r[ct][kk] = w2_s[kk][h];
    }

    float rowsum[4][4];   // [rt][reg]
    for (int rt = 0; rt < 4; rt++) {
        for (int reg = 0; reg < 4; reg++) {
            const int m = rt * 16 + quad * 4 + reg;
            floatx4 bsv = *(const floatx4*)&bs_s[m][0];   // quad-broadcast b128
            float rs = 0.0f;
            for (int ct = 0; ct < 4; ct++) {
                float v = acc[rt][ct][reg] + bm[ct]
                        + bsv[0] * w2r[ct][0] + bsv[1] * w2r[ct][1]
                        + bsv[2] * w2r[ct][2] + bsv[3] * w2r[ct][3];
                rs += fast_tanh(v) * wo[ct];
            }
            // reduce across the quad's 16 lanes (cols)
            rs += __shfl_xor(rs, 1);
            rs += __shfl_xor(rs, 2);
            rs += __shfl_xor(rs, 4);
            rs += __shfl_xor(rs, 8);
            rowsum[rt][reg] = rs;
        }
    }

    if (col16 == 0) {
        for (int rt = 0; rt < 4; rt++)
            for (int reg = 0; reg < 4; reg++)
                red[w][rt * 16 + quad * 4 + reg] = rowsum[rt][reg];
    }
    __syncthreads();

    if (tid < 64) {
        const int m = tid;
        float total = red[0][m] + red[1][m] + red[2][m] + red[3][m];
        const int p = p0 + (m >> 3), a = a0 + (m & 7);
        out[((size_t)(b * LSEQ + p) * NCASE + n) * LSEQ + a] = total;
    }
}

// ---------------------------------------------------------------------------
extern "C" void kernel_launch(void* const* d_in, const int* in_sizes, int n_in,
                              void* d_out, int out_size, void* d_ws, size_t ws_size,
                              hipStream_t stream) {
    const float* seq  = (const float*)d_in[0];
    const float* bsc  = (const float*)d_in[1];
    const float* Wp   = (const float*)d_in[2];
    const float* bp   = (const float*)d_in[3];
    const float* Wa   = (const float*)d_in[4];
    const float* ba   = (const float*)d_in[5];
    const float* Wmid = (const float*)d_in[6];
    const float* bmid = (const float*)d_in[7];
    const float* Wout = (const float*)d_in[8];
    float* out = (float*)d_out;

    float*  lin   = (float*)d_ws;                              // 384*1280 fp32 = 1.97 MB
    __bf16* Bpack = (__bf16*)((char*)d_ws + (2u << 20));       // 512 KB packed Wmid

    // lin accumulated via atomicAdd -> zero it every call (ws is re-poisoned)
    hipMemsetAsync(lin, 0, (size_t)BATCH * LSEQ * 1280 * sizeof(float), stream);

    pack_wmid<<<(NCASE * 256 * 256) / 256, 256, 0, stream>>>(Wmid, Bpack);
    lin_gemm<<<dim3(6, 20, 4), 256, 0, stream>>>(seq, Wp, Wa, lin);
    refine_main<<<dim3(24 * 24, NCASE, BATCH), 256, 0, stream>>>(
        lin, bsc, Wmid, bmid, Wout, bp, ba, Bpack, out);
}

// Round 2
// 191.967 us; speedup vs baseline: 1.1325x; 1.1325x over previous
//
#include <hip/hip_runtime.h>

// Problem constants (RefinementLayer1): B=2, L=192, D=768, NC=4, H=256
#define LSEQ 192
#define DIM  768
#define NCASE 4
#define HID  256
#define BATCH 2

// tanh(x) = 1 - 2/(exp2(K*x)+1), K = 2*log2(e). K is pre-folded into lin and
// Bpack so the kernels compute tanh with only {exp2, add, rcp, fma}.
#define TANH_K 2.885390081777927f

typedef float  floatx4 __attribute__((ext_vector_type(4)));
typedef __bf16 bf16x8  __attribute__((ext_vector_type(8)));

// input already scaled by TANH_K
__device__ __forceinline__ float tanh_pre(float x) {
    float e = __builtin_amdgcn_exp2f(x);
    return 1.0f - 2.0f * __builtin_amdgcn_rcpf(e + 1.0f);
}

// ---------------------------------------------------------------------------
// Kernel 0: pack Wmid (+ bmid row, + zero pad) into bf16 MFMA B-fragment
// order, scaled by TANH_K. 9 K-chunks of 32:
//   k <  260 : TANH_K * Wmid[n][k][h]     (k in [256,260) = the bs rows)
//   k == 260 : TANH_K * bmid[n][h]        (paired with A=1.0 row)
//   k >  260 : 0
// Fragment: lane holds B[k=(lane>>4)*8+j][h=lane&15], j contiguous.
// Bpack[(((n*9 + kc)*16 + ct)*64 + lane)*8 + j], k=kc*32+..., h=ct*16+...
// ---------------------------------------------------------------------------
__global__ void pack_wmid(const float* __restrict__ Wmid,
                          const float* __restrict__ bmid,
                          __bf16* __restrict__ Bpack) {
    int idx = blockIdx.x * blockDim.x + threadIdx.x;   // 0 .. 4*9*16*512-1
    if (idx >= NCASE * 9 * 16 * 512) return;
    int j    = idx & 7;
    int lane = (idx >> 3) & 63;
    int frag = idx >> 9;          // n*9*16 + kc*16 + ct
    int ct   = frag & 15;
    int nk   = frag >> 4;
    int kc   = nk % 9;
    int n    = nk / 9;
    int k = kc * 32 + (lane >> 4) * 8 + j;
    int h = ct * 16 + (lane & 15);
    float v;
    if (k < 260)       v = Wmid[(n * 260 + k) * 256 + h];
    else if (k == 260) v = bmid[n * 256 + h];
    else               v = 0.0f;
    Bpack[idx] = (__bf16)(TANH_K * v);
}

// ---------------------------------------------------------------------------
// Kernel 1: lin[row, col] = TANH_K * (seq[row,:] @ [Wp | Wa][:, col] + bias)
// fp32, split-K=4 via atomicAdd (lin zeroed first). Bias added by ks==0.
// ---------------------------------------------------------------------------
__global__ __launch_bounds__(256) void lin_gemm(const float* __restrict__ seq,
                                                const float* __restrict__ Wp,
                                                const float* __restrict__ Wa,
                                                const float* __restrict__ bp,
                                                const float* __restrict__ ba,
                                                float* __restrict__ lin) {
    const int bm = blockIdx.x;   // 6  tiles of 64 rows
    const int bn = blockIdx.y;   // 20 tiles of 64 cols
    const int ks = blockIdx.z;   // 4  K-splits of 192

    __shared__ float As[16][64];   // transposed: As[k][m]
    __shared__ float Bs[16][64];

    const int tid = threadIdx.x;
    const int tx = tid & 15, ty = tid >> 4;
    const int colg0 = bn * 64;

    float acc[4][4] = {};

    for (int k0 = ks * 192; k0 < ks * 192 + 192; k0 += 16) {
        const int m = tid >> 2, kq = (tid & 3) * 4;
        floatx4 av = *(const floatx4*)(seq + (size_t)(bm * 64 + m) * DIM + k0 + kq);
        const int kk = tid >> 4, cq = (tid & 15) * 4;
        const int colg = colg0 + cq;
        const float* bptr = (colg < 256) ? (Wp + (size_t)(k0 + kk) * HID + colg)
                                         : (Wa + (size_t)(k0 + kk) * (NCASE * HID) + (colg - 256));
        floatx4 bv = *(const floatx4*)bptr;

        __syncthreads();
        for (int i = 0; i < 4; i++) As[kq + i][m] = av[i];
        for (int i = 0; i < 4; i++) Bs[kk][cq + i] = bv[i];
        __syncthreads();

        #pragma unroll
        for (int k = 0; k < 16; k++) {
            floatx4 a = *(const floatx4*)&As[k][ty * 4];   // b128
            floatx4 b = *(const floatx4*)&Bs[k][tx * 4];   // b128
            #pragma unroll
            for (int i = 0; i < 4; i++)
                #pragma unroll
                for (int j = 0; j < 4; j++)
                    acc[i][j] += a[i] * b[j];
        }
    }
    #pragma unroll
    for (int i = 0; i < 4; i++)
        #pragma unroll
        for (int j = 0; j < 4; j++) {
            const int col = colg0 + tx * 4 + j;
            float v = acc[i][j];
            if (ks == 0) v += (col < 256) ? bp[col] : ba[col - 256];
            atomicAdd(&lin[(size_t)(bm * 64 + ty * 4 + i) * 1280 + col],
                      v * TANH_K);
        }
}

// ---------------------------------------------------------------------------
// Kernel 2: fused main. Per block: fixed (b, n), 64-row tile (8 p x 8 a),
// full N=256, 4 waves each owning 64 cols. K-loop: 8 tanh chunks (pipelined,
// double-buffered LDS, ONE barrier per chunk) + 1 folded bs/bias chunk.
// Epilogue: tanh(acc) . Wout, 16-lane shuffle reduce, cross-wave LDS reduce.
// MFMA layouts (m89/m91-verified):
//   A: lane holds A[m=lane&15][k=(lane>>4)*8+j]
//   B: lane holds B[k=(lane>>4)*8+j][h=lane&15]
//   C/D: lane reg holds D[row=(lane>>4)*4+reg][col=lane&15]
// ---------------------------------------------------------------------------
__global__ __launch_bounds__(256) void refine_main(
    const float* __restrict__ lin,        // [384][1280], pre-scaled by TANH_K
    const float* __restrict__ base_score, // [B][L][NC][L]
    const float* __restrict__ Wout,       // [NC][256]
    const __bf16* __restrict__ Bpack,     // packed Wmid bf16, 9 chunks
    float* __restrict__ out)              // [B][L][NC][L]
{
    const int bx = blockIdx.x;            // 576 = 24*24
    const int n  = blockIdx.y;
    const int b  = blockIdx.z;
    const int ptile = bx / 24, atile = bx % 24;
    const int p0 = ptile * 8, a0 = atile * 8;

    const int tid   = threadIdx.x;
    const int w     = tid >> 6;           // wave 0..3, owns cols [w*64, w*64+64)
    const int lane  = tid & 63;
    const int quad  = lane >> 4;
    const int col16 = lane & 15;

    __shared__ bf16x8 Alds[2][256];       // double-buffered A-frags, 8 KB
    __shared__ float  bs_s[64][4];        // bs[m][c] = base_score[b,p(m),c,a(m)]
    __shared__ float  wo_s[256];          // Wout[n]
    __shared__ float  red[4][64];         // cross-wave row partials

    // ---- preload per-block data (ordered before use by the loop barriers)
    wo_s[tid] = Wout[n * 256 + tid];
    {
        int row = tid >> 2, kk = tid & 3;
        int p = p0 + (row >> 3), a = a0 + (row & 7);
        bs_s[row][kk] = base_score[((size_t)(b * LSEQ + p) * NCASE + kk) * LSEQ + a];
    }

    // A-gen: thread owns row m = w*16 + col16, k-slice quad*8 .. +7 per chunk
    const int m_gen = w * 16 + col16;
    const int pg = p0 + (m_gen >> 3), ag = a0 + (m_gen & 7);
    const float* hp_ptr = lin + (size_t)(b * LSEQ + pg) * 1280 + quad * 8;
    const float* ha_ptr = lin + (size_t)(b * LSEQ + ag) * 1280 + 256 + n * 256 + quad * 8;
    const __bf16* bp_frag = Bpack + (size_t)n * (9 * 16 * 512) + lane * 8;

    floatx4 acc[4][4] = {};   // [rt][ct]

    floatx4 hp0 = *(const floatx4*)(hp_ptr);
    floatx4 hp1 = *(const floatx4*)(hp_ptr + 4);
    floatx4 ha0 = *(const floatx4*)(ha_ptr);
    floatx4 ha1 = *(const floatx4*)(ha_ptr + 4);

    #pragma unroll
    for (int kc = 0; kc < 8; kc++) {
        // B-frags for this chunk: issued now, consumed after the barrier
        bf16x8 bf[4];
        #pragma unroll
        for (int ct = 0; ct < 4; ct++)
            bf[ct] = *(const bf16x8*)(bp_frag + (size_t)(kc * 16 + w * 4 + ct) * 512);

        floatx4 s0 = hp0 + ha0;           // v_pk_add_f32
        floatx4 s1 = hp1 + ha1;

        if (kc < 7) {                     // prefetch next chunk's A inputs
            hp0 = *(const floatx4*)(hp_ptr + (kc + 1) * 32);
            hp1 = *(const floatx4*)(hp_ptr + (kc + 1) * 32 + 4);
            ha0 = *(const floatx4*)(ha_ptr + (kc + 1) * 32);
            ha1 = *(const floatx4*)(ha_ptr + (kc + 1) * 32 + 4);
        }

        bf16x8 av;
        #pragma unroll
        for (int j = 0; j < 4; j++) av[j]     = (__bf16)tanh_pre(s0[j]);
        #pragma unroll
        for (int j = 0; j < 4; j++) av[4 + j] = (__bf16)tanh_pre(s1[j]);
        Alds[kc & 1][tid] = av;
        __syncthreads();                  // single barrier per chunk (dbuf)

        bf16x8 af[4];
        #pragma unroll
        for (int rt = 0; rt < 4; rt++) af[rt] = Alds[kc & 1][rt * 64 + lane];
        #pragma unroll
        for (int rt = 0; rt < 4; rt++)
            #pragma unroll
            for (int ct = 0; ct < 4; ct++)
                acc[rt][ct] = __builtin_amdgcn_mfma_f32_16x16x32_bf16(
                    af[rt], bf[ct], acc[rt][ct], 0, 0, 0);
    }

    // ---- chunk 8: A = [bs(4), 1, 0...], B = TANH_K*[Wmid[256:260], bmid, 0...]
    {
        bf16x8 bf[4];
        #pragma unroll
        for (int ct = 0; ct < 4; ct++)
            bf[ct] = *(const bf16x8*)(bp_frag + (size_t)(8 * 16 + w * 4 + ct) * 512);

        bf16x8 av = {};
        if (quad == 0) {
            #pragma unroll
            for (int j = 0; j < 4; j++) av[j] = (__bf16)bs_s[m_gen][j];
            av[4] = (__bf16)1.0f;
        }
        Alds[0][tid] = av;   // last write was buf1 (kc=7); buf0 reads were kc=6
        __syncthreads();

        bf16x8 af[4];
        #pragma unroll
        for (int rt = 0; rt < 4; rt++) af[rt] = Alds[0][rt * 64 + lane];
        #pragma unroll
        for (int rt = 0; rt < 4; rt++)
            #pragma unroll
            for (int ct = 0; ct < 4; ct++)
                acc[rt][ct] = __builtin_amdgcn_mfma_f32_16x16x32_bf16(
                    af[rt], bf[ct], acc[rt][ct], 0, 0, 0);
    }

    // ---- epilogue: tanh(acc) . Wout, reduce over h
    float wo[4];
    #pragma unroll
    for (int ct = 0; ct < 4; ct++) wo[ct] = wo_s[w * 64 + ct * 16 + col16];

    #pragma unroll
    for (int rt = 0; rt < 4; rt++) {
        #pragma unroll
        for (int reg = 0; reg < 4; reg++) {
            float rs = 0.0f;
            #pragma unroll
            for (int ct = 0; ct < 4; ct++)
                rs += tanh_pre(acc[rt][ct][reg]) * wo[ct];
            rs += __shfl_xor(rs, 1);
            rs += __shfl_xor(rs, 2);
            rs += __shfl_xor(rs, 4);
            rs += __shfl_xor(rs, 8);
            if (col16 == 0) red[w][rt * 16 + quad * 4 + reg] = rs;
        }
    }
    __syncthreads();

    if (tid < 64) {
        const int m = tid;
        float total = red[0][m] + red[1][m] + red[2][m] + red[3][m];
        const int p = p0 + (m >> 3), a = a0 + (m & 7);
        out[((size_t)(b * LSEQ + p) * NCASE + n) * LSEQ + a] = total;
    }
}

// ---------------------------------------------------------------------------
extern "C" void kernel_launch(void* const* d_in, const int* in_sizes, int n_in,
                              void* d_out, int out_size, void* d_ws, size_t ws_size,
                              hipStream_t stream) {
    const float* seq  = (const float*)d_in[0];
    const float* bsc  = (const float*)d_in[1];
    const float* Wp   = (const float*)d_in[2];
    const float* bp   = (const float*)d_in[3];
    const float* Wa   = (const float*)d_in[4];
    const float* ba   = (const float*)d_in[5];
    const float* Wmid = (const float*)d_in[6];
    const float* bmid = (const float*)d_in[7];
    const float* Wout = (const float*)d_in[8];
    float* out = (float*)d_out;

    float*  lin   = (float*)d_ws;                        // 384*1280 fp32 = 1.97 MB
    __bf16* Bpack = (__bf16*)((char*)d_ws + (2u << 20)); // 576 KB packed Wmid

    // lin accumulated via atomicAdd -> zero it every call (ws is re-poisoned)
    hipMemsetAsync(lin, 0, (size_t)BATCH * LSEQ * 1280 * sizeof(float), stream);

    pack_wmid<<<(NCASE * 9 * 16 * 512) / 256, 256, 0, stream>>>(Wmid, bmid, Bpack);
    lin_gemm<<<dim3(6, 20, 4), 256, 0, stream>>>(seq, Wp, Wa, bp, ba, lin);
    refine_main<<<dim3(24 * 24, NCASE, BATCH), 256, 0, stream>>>(
        lin, bsc, Wout, Bpack, out);
}